// Round 1
// baseline (3831.762 us; speedup 1.0000x reference)
//
#include <hip/hip_runtime.h>
#include <cstdint>
#include <cstddef>

#define DI __device__ __forceinline__

// psum ADC quantization: clip(round_half_even(p/16), -8, 7) * 16
DI float pq16(float ps) {
    float q = rintf(ps * 0.0625f);
    q = fminf(7.f, fmaxf(-8.f, q));
    return q * 16.f;
}

DI float bnv(float x, float g, float b, float m, float v) {
    return (x - m) * (g / sqrtf(v + 1e-5f)) + b;
}

// ---------------- conv0 (full precision) + bn0 + sign -> int8 ----------------
__global__ __launch_bounds__(256)
void k_conv0(const float* __restrict__ x, const float* __restrict__ w,
             const float* __restrict__ bnp, signed char* __restrict__ out) {
    int idx = blockIdx.x * 256 + threadIdx.x;           // over 64*128*32*32
    int xx = idx & 31, yy = (idx >> 5) & 31, o = (idx >> 10) & 127, b = idx >> 17;
    float acc = 0.f;
    #pragma unroll
    for (int c = 0; c < 3; ++c) {
        const float* xp = x + ((b * 3 + c) * 32) * 32;
        const float* wp = w + (o * 3 + c) * 9;
        #pragma unroll
        for (int ky = 0; ky < 3; ++ky) {
            int y = yy + ky - 1;
            if ((unsigned)y >= 32u) continue;
            #pragma unroll
            for (int kx = 0; kx < 3; ++kx) {
                int x2 = xx + kx - 1;
                if ((unsigned)x2 >= 32u) continue;
                acc += xp[y * 32 + x2] * wp[ky * 3 + kx];
            }
        }
    }
    float val = bnv(acc, bnp[o], bnp[128 + o], bnp[256 + o], bnp[384 + o]);
    out[idx] = val >= 0.f ? (signed char)1 : (signed char)-1;
}

// ---------------- crossbar psum conv: groups of 14 channels, quantize, sum ---
// Each thread computes 4 consecutive x-outputs for one output channel.
// TILE=16 -> 64 threads per o-slice, OPB=4 (wave-uniform o).
// TILE=8  -> 16 threads per o-slice, OPB=16.
template <int TILE, int OPB>
__global__ __launch_bounds__(256)
void k_psum_conv(const signed char* __restrict__ act, const float* __restrict__ w,
                 float* __restrict__ out, int Cin, int O, int H, int G) {
    constexpr int CHUNK = 14;
    constexpr int S = TILE * (TILE / 4);
    static_assert(S * OPB == 256, "block mismatch");
    constexpr int AST = (TILE + 2 + 3) & ~3;  // padded LDS row stride (dwords)

    __shared__ __align__(16) float sA[CHUNK][TILE + 2][AST];
    __shared__ __align__(16) float sW[OPB][CHUNK][9];

    const int tid = threadIdx.x;
    const int ntx = H / TILE;
    const int tileY = (int)blockIdx.x / ntx, tileX = (int)blockIdx.x % ntx;
    const int o0 = blockIdx.y * OPB;
    const int b  = blockIdx.z;

    const int oo  = tid / S;
    const int r   = tid % S;
    const int ty  = r / (TILE / 4);
    const int txg = (r % (TILE / 4)) * 4;

    float tot0 = 0.f, tot1 = 0.f, tot2 = 0.f, tot3 = 0.f;

    for (int g = 0; g < G; ++g) {
        const int c0 = g * CHUNK;
        // stage activations (zero border + zero pad-channels)
        for (int i = tid; i < CHUNK * (TILE + 2) * (TILE + 2); i += 256) {
            int c = i / ((TILE + 2) * (TILE + 2));
            int rem = i - c * (TILE + 2) * (TILE + 2);
            int yy = rem / (TILE + 2), xx = rem - yy * (TILE + 2);
            int gy = tileY * TILE + yy - 1, gx = tileX * TILE + xx - 1;
            int cg = c0 + c;
            float v = 0.f;
            if (cg < Cin && (unsigned)gy < (unsigned)H && (unsigned)gx < (unsigned)H)
                v = (float)act[(((size_t)b * Cin + cg) * H + gy) * H + gx];
            sA[c][yy][xx] = v;
        }
        // stage signed weights
        for (int i = tid; i < OPB * CHUNK * 9; i += 256) {
            int o_ = i / (CHUNK * 9);
            int rem = i - o_ * (CHUNK * 9);
            int c = rem / 9, k = rem - c * 9;
            int cg = c0 + c;
            float v = 0.f;
            if (cg < Cin)
                v = (w[((size_t)(o0 + o_) * Cin + cg) * 9 + k] >= 0.f) ? 1.f : -1.f;
            sW[o_][c][k] = v;
        }
        __syncthreads();

        float p0 = 0.f, p1 = 0.f, p2 = 0.f, p3 = 0.f;
        #pragma unroll
        for (int c = 0; c < CHUNK; ++c) {
            #pragma unroll
            for (int ky = 0; ky < 3; ++ky) {
                const float* ar = &sA[c][ty + ky][txg];
                float a0 = ar[0], a1 = ar[1], a2 = ar[2];
                float a3 = ar[3], a4 = ar[4], a5 = ar[5];
                float w0 = sW[oo][c][ky * 3 + 0];
                float w1 = sW[oo][c][ky * 3 + 1];
                float w2 = sW[oo][c][ky * 3 + 2];
                p0 += a0 * w0 + a1 * w1 + a2 * w2;
                p1 += a1 * w0 + a2 * w1 + a3 * w2;
                p2 += a2 * w0 + a3 * w1 + a4 * w2;
                p3 += a3 * w0 + a4 * w1 + a5 * w2;
            }
        }
        tot0 += pq16(p0); tot1 += pq16(p1); tot2 += pq16(p2); tot3 += pq16(p3);
        __syncthreads();
    }

    int y = tileY * TILE + ty, xb = tileX * TILE + txg;
    float* op = out + (((size_t)b * O + (o0 + oo)) * H + y) * H + xb;
    float4 res = make_float4(tot0, tot1, tot2, tot3);
    *(float4*)op = res;
}

// ---------------- maxpool2 -> bn -> sign (optional transposed f32 copy) -----
__global__ __launch_bounds__(256)
void k_pool_bn_sign(const float* __restrict__ in, const float* __restrict__ bnp,
                    signed char* __restrict__ out, float* __restrict__ tout,
                    int C, int H) {
    int Ho = H >> 1;
    int idx = blockIdx.x * 256 + threadIdx.x;
    int total = 64 * C * Ho * Ho;
    if (idx >= total) return;
    int x2 = idx % Ho; int t = idx / Ho;
    int y2 = t % Ho; t /= Ho;
    int c = t % C; int b = t / C;
    const float* ip = in + (((size_t)b * C + c) * H + 2 * y2) * H + 2 * x2;
    float mx = fmaxf(fmaxf(ip[0], ip[1]), fmaxf(ip[H], ip[H + 1]));
    float val = bnv(mx, bnp[c], bnp[C + c], bnp[2 * C + c], bnp[3 * C + c]);
    signed char s = (val >= 0.f) ? (signed char)1 : (signed char)-1;
    out[idx] = s;
    if (tout) tout[((size_t)(c * Ho + y2) * Ho + x2) * 64 + b] = (float)s;
}

// ---------------- bn -> sign ----------------
__global__ __launch_bounds__(256)
void k_bn_sign(const float* __restrict__ in, const float* __restrict__ bnp,
               signed char* __restrict__ out, int C, int HW) {
    int idx = blockIdx.x * 256 + threadIdx.x;
    int total = 64 * C * HW;
    if (idx >= total) return;
    int c = (idx / HW) % C;
    float val = bnv(in[idx], bnp[c], bnp[C + c], bnp[2 * C + c], bnp[3 * C + c]);
    out[idx] = (val >= 0.f) ? (signed char)1 : (signed char)-1;
}

// ---------------- psum fc: groups of 128, quantize, sum; bn(+sign) epilogue -
// a_t is [D][64] f32 (+-1), lane = batch -> coalesced.
// SIGN: write a6_t [O][64] f32 +-1.  !SIGN: write h2 [64][O] f32 (bn only).
template <bool SIGN>
__global__ __launch_bounds__(256)
void k_fc(const float* __restrict__ a_t, const float* __restrict__ w,
          const float* __restrict__ bnp, float* __restrict__ out,
          int D, int G, int O) {
    int b = threadIdx.x & 63;
    int o = blockIdx.x * 4 + (threadIdx.x >> 6);
    float tot = 0.f;
    for (int g = 0; g < G; ++g) {
        float ps = 0.f;
        const float* ap = a_t + (size_t)(g * 128) * 64 + b;
        const float* wp = w + (size_t)o * D + g * 128;
        #pragma unroll 4
        for (int c = 0; c < 128; ++c) {
            float a = ap[c * 64];
            float wv = (wp[c] >= 0.f) ? 1.f : -1.f;
            ps += a * wv;
        }
        tot += pq16(ps);
    }
    float val = bnv(tot, bnp[o], bnp[O + o], bnp[2 * O + o], bnp[3 * O + o]);
    if (SIGN) out[(size_t)o * 64 + b] = (val >= 0.f) ? 1.f : -1.f;
    else      out[(size_t)b * O + o] = val;
}

// ---------------- final dense + bias + bn ----------------
__global__ __launch_bounds__(64)
void k_out(const float* __restrict__ h2, const float* __restrict__ ow,
           const float* __restrict__ ob, const float* __restrict__ bnp,
           float* __restrict__ out) {
    int tid = blockIdx.x * 64 + threadIdx.x;
    if (tid >= 640) return;
    int b = tid / 10, o = tid % 10;
    float acc = 0.f;
    for (int k = 0; k < 1024; ++k) acc += h2[b * 1024 + k] * ow[o * 1024 + k];
    acc += ob[o];
    out[tid] = bnv(acc, bnp[o], bnp[10 + o], bnp[20 + o], bnp[30 + o]);
}

extern "C" void kernel_launch(void* const* d_in, const int* in_sizes, int n_in,
                              void* d_out, int out_size, void* d_ws, size_t ws_size,
                              hipStream_t stream) {
    const float* x     = (const float*)d_in[0];
    const float* w0    = (const float*)d_in[1];
    const float* bn0   = (const float*)d_in[2];
    const float* w1    = (const float*)d_in[3];
    const float* bn1   = (const float*)d_in[4];
    const float* w2    = (const float*)d_in[5];
    const float* bn2   = (const float*)d_in[6];
    const float* w3    = (const float*)d_in[7];
    const float* bn3   = (const float*)d_in[8];
    const float* w4    = (const float*)d_in[9];
    const float* bn4   = (const float*)d_in[10];
    const float* w5    = (const float*)d_in[11];
    const float* bn5   = (const float*)d_in[12];
    const float* fc1w  = (const float*)d_in[13];
    const float* bnf1  = (const float*)d_in[14];
    const float* fc2w  = (const float*)d_in[15];
    const float* bnf2  = (const float*)d_in[16];
    const float* outw  = (const float*)d_in[17];
    const float* outb  = (const float*)d_in[18];
    const float* bnout = (const float*)d_in[19];

    char* ws = (char*)d_ws;
    float*       P    = (float*)(ws);                    // 33,554,432 B  (max psum f32)
    signed char* actA = (signed char*)(ws + 33554432);   //  8,388,608 B
    signed char* actB = (signed char*)(ws + 41943040);   //  8,388,608 B
    float*       a5t  = (float*)(ws + 50331648);         //  2,097,152 B  [8192][64]
    float*       a6t  = (float*)(ws + 52428800);         //    262,144 B  [1024][64]
    float*       h2   = (float*)(ws + 52690944);         //    262,144 B  [64][1024]

    // conv0 + bn0 + sign
    k_conv0<<<dim3(32768), dim3(256), 0, stream>>>(x, w0, bn0, actA);
    // layer1: psum_conv 128->128 @32, pool, bn1, sign
    k_psum_conv<16, 4><<<dim3(4, 32, 64), dim3(256), 0, stream>>>(actA, w1, P, 128, 128, 32, 10);
    k_pool_bn_sign<<<dim3(8192), dim3(256), 0, stream>>>(P, bn1, actB, nullptr, 128, 32);
    // layer2: psum_conv 128->256 @16, bn2, sign
    k_psum_conv<16, 4><<<dim3(1, 64, 64), dim3(256), 0, stream>>>(actB, w2, P, 128, 256, 16, 10);
    k_bn_sign<<<dim3(16384), dim3(256), 0, stream>>>(P, bn2, actA, 256, 256);
    // layer3: psum_conv 256->256 @16, pool, bn3, sign
    k_psum_conv<16, 4><<<dim3(1, 64, 64), dim3(256), 0, stream>>>(actA, w3, P, 256, 256, 16, 19);
    k_pool_bn_sign<<<dim3(4096), dim3(256), 0, stream>>>(P, bn3, actB, nullptr, 256, 16);
    // layer4: psum_conv 256->512 @8, bn4, sign
    k_psum_conv<8, 16><<<dim3(1, 32, 64), dim3(256), 0, stream>>>(actB, w4, P, 256, 512, 8, 19);
    k_bn_sign<<<dim3(8192), dim3(256), 0, stream>>>(P, bn4, actA, 512, 64);
    // layer5: psum_conv 512->512 @8, pool, bn5, sign (+ transposed f32 for fc1)
    k_psum_conv<8, 16><<<dim3(1, 32, 64), dim3(256), 0, stream>>>(actA, w5, P, 512, 512, 8, 37);
    k_pool_bn_sign<<<dim3(2048), dim3(256), 0, stream>>>(P, bn5, actB, a5t, 512, 8);
    // fc1: psum_linear D=8192 (G=64), bnf1, sign -> a6t [1024][64]
    k_fc<true><<<dim3(256), dim3(256), 0, stream>>>(a5t, fc1w, bnf1, a6t, 8192, 64, 1024);
    // fc2: psum_linear D=1024 (G=8), bnf2 (no sign) -> h2 [64][1024]
    k_fc<false><<<dim3(256), dim3(256), 0, stream>>>(a6t, fc2w, bnf2, h2, 1024, 8, 1024);
    // out: h2 @ out_w^T + out_b, bnout
    k_out<<<dim3(10), dim3(64), 0, stream>>>(h2, outw, outb, bnout, (float*)d_out);
}

// Round 2
// 1257.068 us; speedup vs baseline: 3.0482x; 3.0482x over previous
//
#include <hip/hip_runtime.h>
#include <cstdint>
#include <cstddef>

using bf16x8 = __attribute__((ext_vector_type(8))) short;
using f32x4  = __attribute__((ext_vector_type(4))) float;
using u32x4  = __attribute__((ext_vector_type(4))) unsigned int;

#define DI __device__ __forceinline__

// psum ADC quantization: clip(round_half_even(p/16), -8, 7) * 16   (exact on int psums)
DI float pq16(float ps) {
    float q = rintf(ps * 0.0625f);
    q = fminf(7.f, fmaxf(-8.f, q));
    return q * 16.f;
}

DI float bnv(float x, float g, float b, float m, float v) {
    return (x - m) * (g / sqrtf(v + 1e-5f)) + b;
}

// ---------------- conv0 (full precision) + bn0 + sign -> bf16 NHWC ----------
__global__ __launch_bounds__(256)
void k_conv0(const float* __restrict__ x, const float* __restrict__ w,
             const float* __restrict__ bnp, unsigned short* __restrict__ out) {
    int idx = blockIdx.x * 256 + threadIdx.x;   // 64*32*32*128, o innermost (NHWC)
    int o = idx & 127, xx = (idx >> 7) & 31, yy = (idx >> 12) & 31, b = idx >> 17;
    float acc = 0.f;
    #pragma unroll
    for (int c = 0; c < 3; ++c) {
        const float* xp = x + ((b * 3 + c) * 32) * 32;
        const float* wp = w + (o * 3 + c) * 9;
        #pragma unroll
        for (int ky = 0; ky < 3; ++ky) {
            int y = yy + ky - 1;
            if ((unsigned)y >= 32u) continue;
            #pragma unroll
            for (int kx = 0; kx < 3; ++kx) {
                int x2 = xx + kx - 1;
                if ((unsigned)x2 >= 32u) continue;
                acc += xp[y * 32 + x2] * wp[ky * 3 + kx];
            }
        }
    }
    float val = bnv(acc, bnp[o], bnp[128 + o], bnp[256 + o], bnp[384 + o]);
    out[idx] = (val >= 0.f) ? (unsigned short)0x3F80 : (unsigned short)0xBF80;
}

// ---------------- weight sign-pack: wpk[g][o][tap(10)][c(16)] bf16 ----------
__global__ __launch_bounds__(256)
void k_pack_w(const float* __restrict__ w, unsigned short* __restrict__ wpk,
              int Cin, int O, int G) {
    int idx = blockIdx.x * 256 + threadIdx.x;
    int total = G * O * 160;
    if (idx >= total) return;
    int c = idx & 15;
    int tap = (idx >> 4) % 10;
    int rest = idx / 160;
    int o = rest % O, g = rest / O;
    unsigned short v = 0;
    int cg = g * 14 + c;
    if (tap < 9 && c < 14 && cg < Cin)
        v = (w[((size_t)o * Cin + cg) * 9 + tap] >= 0.f) ? (unsigned short)0x3F80
                                                         : (unsigned short)0xBF80;
    wpk[idx] = v;
}

// ---------------- MFMA crossbar psum conv, fused bn/sign/pool epilogue ------
// act NHWC bf16 (read as u32). K-order per group: tap-major (10, tap9=zero pad),
// channel-minor (16, ch>=14 or >=Cin zero). 5 MFMA K-steps of 32 per group.
// POOLMODE: 0 = bn+sign -> act NHWC; 1 = pool2+bn+sign -> act NHWC (RW==16);
//           2 = pool2+bn+sign -> a5t [d][64] f32 (RW==8, layer5)
template <int H, int W, int Cin, int O, int G, int RH, int RW, int POOLMODE>
__global__ __launch_bounds__(256)
void k_conv_mfma(const unsigned int* __restrict__ act,
                 const unsigned int* __restrict__ wpk,
                 const float* __restrict__ bnp,
                 unsigned short* __restrict__ outa,
                 float* __restrict__ a5t) {
    constexpr int SH = RH + 2, SW = RW + 2;
    constexpr int MS = RH * RW / 16;          // 16-pixel M-subtiles per region
    constexpr int NREGX = W / RW;
    static_assert(POOLMODE != 1 || RW == 16, "pool mode 1 needs RW=16");
    static_assert(POOLMODE != 2 || (RW == 8 && MS == 4), "pool mode 2 needs 8x8");

    __shared__ __align__(16) unsigned int sA[SH * SW * 12];  // 48B per pixel slot
    __shared__ __align__(16) unsigned int sW[64 * 80];       // 64 o x 10 tap x 16c bf16

    const int tid  = threadIdx.x;
    const int regY = (int)blockIdx.x / NREGX, regX = (int)blockIdx.x % NREGX;
    const int o0   = blockIdx.y * 64;
    const int b    = blockIdx.z;

    const int lane = tid & 63, wv = tid >> 6;
    const int n  = lane & 15;       // A-row (pixel-in-msub) / B-col / D-col roles
    const int kb = lane >> 4;
    const int hb = kb >> 1, ch = kb & 1;

    // per-lane A base byte offsets (pixel role: m = lane&15)
    int baseA[MS];
    #pragma unroll
    for (int ms = 0; ms < MS; ++ms) {
        int p = ms * 16 + n;
        int y = p / RW, x = p % RW;
        baseA[ms] = (y * SW + x) * 48 + ch * 16;
    }

    float tot[MS][4];
    #pragma unroll
    for (int ms = 0; ms < MS; ++ms) {
        tot[ms][0] = 0.f; tot[ms][1] = 0.f; tot[ms][2] = 0.f; tot[ms][3] = 0.f;
    }

    #pragma unroll 1
    for (int g = 0; g < G; ++g) {
        const int rem_dw = (Cin - g * 14) >> 1;   // valid channel-dwords this group
        // stage A tile (halo'd, zero border / zero pad-channels)
        for (int i = tid; i < SH * SW * 8; i += 256) {
            int cp = i & 7, slot = i >> 3;
            int yy = slot / SW, xx = slot - yy * SW;
            int gy = regY * RH + yy - 1, gx = regX * RW + xx - 1;
            unsigned int v = 0;
            if (cp < 7 && cp < rem_dw &&
                (unsigned)gy < (unsigned)H && (unsigned)gx < (unsigned)W)
                v = act[(((size_t)b * H + gy) * W + gx) * (Cin / 2) + g * 7 + cp];
            sA[slot * 12 + cp] = v;
        }
        // stage W tile (contiguous 20480 B)
        {
            const u32x4* src = (const u32x4*)(wpk + (size_t)(g * O + o0) * 80);
            u32x4* dst = (u32x4*)sW;
            for (int i = tid; i < 1280; i += 256) dst[i] = src[i];
        }
        __syncthreads();

        // hoist this wave's B fragments (16 output channels) to registers
        const unsigned short* sWu = (const unsigned short*)sW;
        bf16x8 bq[5];
        #pragma unroll
        for (int s = 0; s < 5; ++s) {
            int tap = 2 * s + hb;   // <=9
            bq[s] = *(const bf16x8*)&sWu[(wv * 16 + n) * 160 + tap * 16 + ch * 8];
        }

        const char* sAc = (const char*)sA;
        #pragma unroll
        for (int ms = 0; ms < MS; ++ms) {
            f32x4 acc = {0.f, 0.f, 0.f, 0.f};
            #pragma unroll
            for (int s = 0; s < 5; ++s) {
                const int t0 = 2 * s, t1 = 2 * s + 1;
                const int off0 = ((t0 / 3) * SW + (t0 % 3)) * 48;
                const int off1 = (t1 >= 9) ? 0 : ((t1 / 3) * SW + (t1 % 3)) * 48;
                int off = hb ? off1 : off0;
                bf16x8 af = *(const bf16x8*)(sAc + baseA[ms] + off);
                acc = __builtin_amdgcn_mfma_f32_16x16x32_bf16(af, bq[s], acc, 0, 0, 0);
            }
            tot[ms][0] += pq16(acc[0]);
            tot[ms][1] += pq16(acc[1]);
            tot[ms][2] += pq16(acc[2]);
            tot[ms][3] += pq16(acc[3]);
        }
        __syncthreads();
    }

    // ---- epilogue (D layout: lane holds pixels m=4*kb+r, channel n=lane&15) ----
    const int oc = o0 + wv * 16 + n;
    const float bg = bnp[oc], bb = bnp[O + oc], bm = bnp[2 * O + oc], bvr = bnp[3 * O + oc];

    if constexpr (POOLMODE == 0) {
        #pragma unroll
        for (int ms = 0; ms < MS; ++ms)
            #pragma unroll
            for (int r = 0; r < 4; ++r) {
                int p = ms * 16 + 4 * kb + r;
                int y = regY * RH + p / RW, x = regX * RW + p % RW;
                float val = bnv(tot[ms][r], bg, bb, bm, bvr);
                outa[(((size_t)b * H + y) * W + x) * O + oc] =
                    (val >= 0.f) ? (unsigned short)0x3F80 : (unsigned short)0xBF80;
            }
    } else if constexpr (POOLMODE == 1) {
        // RW=16: ms = row y in region; x = 4*kb + r (all pool partners in-lane)
        #pragma unroll
        for (int j = 0; j < MS / 2; ++j)
            #pragma unroll
            for (int q = 0; q < 2; ++q) {
                float v = fmaxf(fmaxf(tot[2 * j][2 * q], tot[2 * j][2 * q + 1]),
                                fmaxf(tot[2 * j + 1][2 * q], tot[2 * j + 1][2 * q + 1]));
                float val = bnv(v, bg, bb, bm, bvr);
                int py = regY * (RH / 2) + j, px = regX * (RW / 2) + 2 * kb + q;
                outa[(((size_t)b * (H / 2) + py) * (W / 2) + px) * O + oc] =
                    (val >= 0.f) ? (unsigned short)0x3F80 : (unsigned short)0xBF80;
            }
    } else {
        // RW=8: y = 2*ms + hb, x = 4*ch + r; vertical partner = lane ^ 32
        #pragma unroll
        for (int ms = 0; ms < MS; ++ms)
            #pragma unroll
            for (int q = 0; q < 2; ++q) {
                float h = fmaxf(tot[ms][2 * q], tot[ms][2 * q + 1]);
                float o2 = __shfl_xor(h, 32);
                float v = fmaxf(h, o2);
                if (hb == 0) {
                    float val = bnv(v, bg, bb, bm, bvr);
                    int d = oc * 16 + ms * 4 + 2 * ch + q;   // NCHW flatten order
                    a5t[(size_t)d * 64 + b] = (val >= 0.f) ? 1.f : -1.f;
                }
            }
    }
}

// ---------------- psum fc: groups of 128, quantize, sum; bn(+sign) epilogue -
template <bool SIGN>
__global__ __launch_bounds__(256)
void k_fc(const float* __restrict__ a_t, const float* __restrict__ w,
          const float* __restrict__ bnp, float* __restrict__ out,
          int D, int G, int O) {
    int b = threadIdx.x & 63;
    int o = blockIdx.x * 4 + (threadIdx.x >> 6);
    float tot = 0.f;
    for (int g = 0; g < G; ++g) {
        float ps = 0.f;
        const float* ap = a_t + (size_t)(g * 128) * 64 + b;
        const float* wp = w + (size_t)o * D + g * 128;
        #pragma unroll 4
        for (int c = 0; c < 128; ++c) {
            float a = ap[c * 64];
            float wv = (wp[c] >= 0.f) ? 1.f : -1.f;
            ps += a * wv;
        }
        tot += pq16(ps);
    }
    float val = bnv(tot, bnp[o], bnp[O + o], bnp[2 * O + o], bnp[3 * O + o]);
    if (SIGN) out[(size_t)o * 64 + b] = (val >= 0.f) ? 1.f : -1.f;
    else      out[(size_t)b * O + o] = val;
}

// ---------------- final dense + bias + bn ----------------
__global__ __launch_bounds__(64)
void k_out(const float* __restrict__ h2, const float* __restrict__ ow,
           const float* __restrict__ ob, const float* __restrict__ bnp,
           float* __restrict__ out) {
    int tid = blockIdx.x * 64 + threadIdx.x;
    if (tid >= 640) return;
    int b = tid / 10, o = tid % 10;
    float acc = 0.f;
    for (int k = 0; k < 1024; ++k) acc += h2[b * 1024 + k] * ow[o * 1024 + k];
    acc += ob[o];
    out[tid] = bnv(acc, bnp[o], bnp[10 + o], bnp[20 + o], bnp[30 + o]);
}

extern "C" void kernel_launch(void* const* d_in, const int* in_sizes, int n_in,
                              void* d_out, int out_size, void* d_ws, size_t ws_size,
                              hipStream_t stream) {
    const float* x     = (const float*)d_in[0];
    const float* w0    = (const float*)d_in[1];
    const float* bn0   = (const float*)d_in[2];
    const float* w1    = (const float*)d_in[3];
    const float* bn1   = (const float*)d_in[4];
    const float* w2    = (const float*)d_in[5];
    const float* bn2   = (const float*)d_in[6];
    const float* w3    = (const float*)d_in[7];
    const float* bn3   = (const float*)d_in[8];
    const float* w4    = (const float*)d_in[9];
    const float* bn4   = (const float*)d_in[10];
    const float* w5    = (const float*)d_in[11];
    const float* bn5   = (const float*)d_in[12];
    const float* fc1w  = (const float*)d_in[13];
    const float* bnf1  = (const float*)d_in[14];
    const float* fc2w  = (const float*)d_in[15];
    const float* bnf2  = (const float*)d_in[16];
    const float* outw  = (const float*)d_in[17];
    const float* outb  = (const float*)d_in[18];
    const float* bnout = (const float*)d_in[19];

    char* ws = (char*)d_ws;
    unsigned short* actA = (unsigned short*)(ws);              // 16,777,216 B
    unsigned short* actB = (unsigned short*)(ws + 16777216);   //  4,194,304 B
    unsigned short* wpk  = (unsigned short*)(ws + 20971520);   //  6,291,456 B
    float*          a5t  = (float*)(ws + 27262976);            //  2,097,152 B [8192][64]
    float*          a6t  = (float*)(ws + 29360128);            //    262,144 B [1024][64]
    float*          h2   = (float*)(ws + 29622272);            //    262,144 B [64][1024]

    const unsigned int* actA32 = (const unsigned int*)actA;
    const unsigned int* actB32 = (const unsigned int*)actB;
    const unsigned int* wpk32  = (const unsigned int*)wpk;

    // conv0 + bn0 + sign -> actA NHWC bf16 [64,32,32,128]
    k_conv0<<<dim3(32768), dim3(256), 0, stream>>>(x, w0, bn0, actA);

    // L1: 128->128 @32, pool -> actB [64,16,16,128]
    k_pack_w<<<dim3(800), dim3(256), 0, stream>>>(w1, wpk, 128, 128, 10);
    k_conv_mfma<32, 32, 128, 128, 10, 8, 16, 1>
        <<<dim3(8, 2, 64), dim3(256), 0, stream>>>(actA32, wpk32, bn1, actB, nullptr);

    // L2: 128->256 @16 -> actA [64,16,16,256]
    k_pack_w<<<dim3(1600), dim3(256), 0, stream>>>(w2, wpk, 128, 256, 10);
    k_conv_mfma<16, 16, 128, 256, 10, 8, 16, 0>
        <<<dim3(2, 4, 64), dim3(256), 0, stream>>>(actB32, wpk32, bn2, actA, nullptr);

    // L3: 256->256 @16, pool -> actB [64,8,8,256]
    k_pack_w<<<dim3(3040), dim3(256), 0, stream>>>(w3, wpk, 256, 256, 19);
    k_conv_mfma<16, 16, 256, 256, 19, 8, 16, 1>
        <<<dim3(2, 4, 64), dim3(256), 0, stream>>>(actA32, wpk32, bn3, actB, nullptr);

    // L4: 256->512 @8 -> actA [64,8,8,512]
    k_pack_w<<<dim3(6080), dim3(256), 0, stream>>>(w4, wpk, 256, 512, 19);
    k_conv_mfma<8, 8, 256, 512, 19, 8, 8, 0>
        <<<dim3(1, 8, 64), dim3(256), 0, stream>>>(actB32, wpk32, bn4, actA, nullptr);

    // L5: 512->512 @8, pool -> a5t [8192][64] f32 (+-1)
    k_pack_w<<<dim3(11840), dim3(256), 0, stream>>>(w5, wpk, 512, 512, 37);
    k_conv_mfma<8, 8, 512, 512, 37, 8, 8, 2>
        <<<dim3(1, 8, 64), dim3(256), 0, stream>>>(actA32, wpk32, bn5, nullptr, a5t);

    // fc1 / fc2 / out
    k_fc<true><<<dim3(256), dim3(256), 0, stream>>>(a5t, fc1w, bnf1, a6t, 8192, 64, 1024);
    k_fc<false><<<dim3(256), dim3(256), 0, stream>>>(a6t, fc2w, bnf2, h2, 1024, 8, 1024);
    k_out<<<dim3(10), dim3(64), 0, stream>>>(h2, outw, outb, bnout, (float*)d_out);
}

// Round 4
// 641.939 us; speedup vs baseline: 5.9690x; 1.9582x over previous
//
#include <hip/hip_runtime.h>
#include <cstdint>
#include <cstddef>

using bf16x8 = __attribute__((ext_vector_type(8))) short;
using f32x4  = __attribute__((ext_vector_type(4))) float;
using u32x4  = __attribute__((ext_vector_type(4))) unsigned int;

#define DI __device__ __forceinline__

// psum ADC quantization: clip(round_half_even(p/16), -8, 7) * 16   (exact on int psums)
DI float pq16(float ps) {
    float q = rintf(ps * 0.0625f);
    q = fminf(7.f, fmaxf(-8.f, q));
    return q * 16.f;
}

DI float bnv(float x, float g, float b, float m, float v) {
    return (x - m) * (g / sqrtf(v + 1e-5f)) + b;
}

DI unsigned short sgn_bf16(float v) {
    return (v >= 0.f) ? (unsigned short)0x3F80 : (unsigned short)0xBF80;
}

// ---------------- conv0 (full precision) + bn0 + sign -> bf16 NHWC ----------
__global__ __launch_bounds__(256)
void k_conv0(const float* __restrict__ x, const float* __restrict__ w,
             const float* __restrict__ bnp, unsigned short* __restrict__ out) {
    int idx = blockIdx.x * 256 + threadIdx.x;   // 64*32*32*128, o innermost (NHWC)
    int o = idx & 127, xx = (idx >> 7) & 31, yy = (idx >> 12) & 31, b = idx >> 17;
    float acc = 0.f;
    #pragma unroll
    for (int c = 0; c < 3; ++c) {
        const float* xp = x + ((b * 3 + c) * 32) * 32;
        const float* wp = w + (o * 3 + c) * 9;
        #pragma unroll
        for (int ky = 0; ky < 3; ++ky) {
            int y = yy + ky - 1;
            if ((unsigned)y >= 32u) continue;
            #pragma unroll
            for (int kx = 0; kx < 3; ++kx) {
                int x2 = xx + kx - 1;
                if ((unsigned)x2 >= 32u) continue;
                acc += xp[y * 32 + x2] * wp[ky * 3 + kx];
            }
        }
    }
    float val = bnv(acc, bnp[o], bnp[128 + o], bnp[256 + o], bnp[384 + o]);
    out[idx] = sgn_bf16(val);
}

// ---------------- weight sign-pack: wpk[g][o][tap(10)][c(16)] bf16 ----------
__global__ __launch_bounds__(256)
void k_pack_w(const float* __restrict__ w, unsigned short* __restrict__ wpk,
              int Cin, int O, int G) {
    int idx = blockIdx.x * 256 + threadIdx.x;
    int total = G * O * 160;
    if (idx >= total) return;
    int c = idx & 15;
    int tap = (idx >> 4) % 10;
    int rest = idx / 160;
    int o = rest % O, g = rest / O;
    unsigned short v = 0;
    int cg = g * 14 + c;
    if (tap < 9 && c < 14 && cg < Cin)
        v = sgn_bf16(w[((size_t)o * Cin + cg) * 9 + tap]);
    wpk[idx] = v;
}

// ---------------- MFMA crossbar psum conv, fused bn/sign/pool epilogue ------
// act NHWC bf16 (read as u32). K-order per group: tap-major (10, tap9=zero pad),
// channel-minor (16, ch>=14 or >=Cin zero). 5 MFMA K-steps of 32 per group.
// POOLMODE: 0 = bn+sign -> act NHWC; 1 = pool2+bn+sign -> act NHWC (RW==16);
//           2 = pool2+bn+sign -> a5p B-packed bf16 (RW==8, layer5)
template <int H, int W, int Cin, int O, int G, int RH, int RW, int POOLMODE>
__global__ __launch_bounds__(256)
void k_conv_mfma(const unsigned int* __restrict__ act,
                 const unsigned int* __restrict__ wpk,
                 const float* __restrict__ bnp,
                 unsigned short* __restrict__ outa,
                 unsigned short* __restrict__ a5p) {
    constexpr int SH = RH + 2, SW = RW + 2;
    constexpr int MS = RH * RW / 16;          // 16-pixel M-subtiles per region
    constexpr int NREGX = W / RW;
    static_assert(POOLMODE != 1 || RW == 16, "pool mode 1 needs RW=16");
    static_assert(POOLMODE != 2 || (RW == 8 && MS == 4), "pool mode 2 needs 8x8");

    __shared__ __align__(16) unsigned int sA[SH * SW * 12];  // 48B per pixel slot
    __shared__ __align__(16) unsigned int sW[64 * 80];       // 64 o x 10 tap x 16c bf16

    const int tid  = threadIdx.x;
    const int regY = (int)blockIdx.x / NREGX, regX = (int)blockIdx.x % NREGX;
    const int o0   = blockIdx.y * 64;
    const int b    = blockIdx.z;

    const int lane = tid & 63, wv = tid >> 6;
    const int n  = lane & 15;
    const int kb = lane >> 4;
    const int hb = kb >> 1, ch = kb & 1;

    int baseA[MS];
    #pragma unroll
    for (int ms = 0; ms < MS; ++ms) {
        int p = ms * 16 + n;
        int y = p / RW, x = p % RW;
        baseA[ms] = (y * SW + x) * 48 + ch * 16;
    }

    float tot[MS][4];
    #pragma unroll
    for (int ms = 0; ms < MS; ++ms) {
        tot[ms][0] = 0.f; tot[ms][1] = 0.f; tot[ms][2] = 0.f; tot[ms][3] = 0.f;
    }

    #pragma unroll 1
    for (int g = 0; g < G; ++g) {
        const int rem_dw = (Cin - g * 14) >> 1;
        for (int i = tid; i < SH * SW * 8; i += 256) {
            int cp = i & 7, slot = i >> 3;
            int yy = slot / SW, xx = slot - yy * SW;
            int gy = regY * RH + yy - 1, gx = regX * RW + xx - 1;
            unsigned int v = 0;
            if (cp < 7 && cp < rem_dw &&
                (unsigned)gy < (unsigned)H && (unsigned)gx < (unsigned)W)
                v = act[(((size_t)b * H + gy) * W + gx) * (Cin / 2) + g * 7 + cp];
            sA[slot * 12 + cp] = v;
        }
        {
            const u32x4* src = (const u32x4*)(wpk + (size_t)(g * O + o0) * 80);
            u32x4* dst = (u32x4*)sW;
            for (int i = tid; i < 1280; i += 256) dst[i] = src[i];
        }
        __syncthreads();

        const unsigned short* sWu = (const unsigned short*)sW;
        bf16x8 bq[5];
        #pragma unroll
        for (int s = 0; s < 5; ++s) {
            int tap = 2 * s + hb;
            bq[s] = *(const bf16x8*)&sWu[(wv * 16 + n) * 160 + tap * 16 + ch * 8];
        }

        const char* sAc = (const char*)sA;
        #pragma unroll
        for (int ms = 0; ms < MS; ++ms) {
            f32x4 acc = {0.f, 0.f, 0.f, 0.f};
            #pragma unroll
            for (int s = 0; s < 5; ++s) {
                const int t0 = 2 * s, t1 = 2 * s + 1;
                const int off0 = ((t0 / 3) * SW + (t0 % 3)) * 48;
                const int off1 = (t1 >= 9) ? 0 : ((t1 / 3) * SW + (t1 % 3)) * 48;
                int off = hb ? off1 : off0;
                bf16x8 af = *(const bf16x8*)(sAc + baseA[ms] + off);
                acc = __builtin_amdgcn_mfma_f32_16x16x32_bf16(af, bq[s], acc, 0, 0, 0);
            }
            tot[ms][0] += pq16(acc[0]);
            tot[ms][1] += pq16(acc[1]);
            tot[ms][2] += pq16(acc[2]);
            tot[ms][3] += pq16(acc[3]);
        }
        __syncthreads();
    }

    const int oc = o0 + wv * 16 + n;
    const float bg = bnp[oc], bb = bnp[O + oc], bm = bnp[2 * O + oc], bvr = bnp[3 * O + oc];

    if constexpr (POOLMODE == 0) {
        #pragma unroll
        for (int ms = 0; ms < MS; ++ms)
            #pragma unroll
            for (int r = 0; r < 4; ++r) {
                int p = ms * 16 + 4 * kb + r;
                int y = regY * RH + p / RW, x = regX * RW + p % RW;
                float val = bnv(tot[ms][r], bg, bb, bm, bvr);
                outa[(((size_t)b * H + y) * W + x) * O + oc] = sgn_bf16(val);
            }
    } else if constexpr (POOLMODE == 1) {
        #pragma unroll
        for (int j = 0; j < MS / 2; ++j)
            #pragma unroll
            for (int q = 0; q < 2; ++q) {
                float v = fmaxf(fmaxf(tot[2 * j][2 * q], tot[2 * j][2 * q + 1]),
                                fmaxf(tot[2 * j + 1][2 * q], tot[2 * j + 1][2 * q + 1]));
                float val = bnv(v, bg, bb, bm, bvr);
                int py = regY * (RH / 2) + j, px = regX * (RW / 2) + 2 * kb + q;
                outa[(((size_t)b * (H / 2) + py) * (W / 2) + px) * O + oc] = sgn_bf16(val);
            }
    } else {
        #pragma unroll
        for (int ms = 0; ms < MS; ++ms)
            #pragma unroll
            for (int q = 0; q < 2; ++q) {
                float h = fmaxf(tot[ms][2 * q], tot[ms][2 * q + 1]);
                float o2 = __shfl_xor(h, 32);
                float v = fmaxf(h, o2);
                if (hb == 0) {
                    float val = bnv(v, bg, bb, bm, bvr);
                    int d = oc * 16 + ms * 4 + 2 * ch + q;   // NCHW flatten order
                    a5p[((size_t)(d >> 3) * 64 + b) * 8 + (d & 7)] = sgn_bf16(val);
                }
            }
    }
}

// ---------------- MFMA psum fc: wave owns 16 o-rows x 64 batch --------------
// bpk: B-packed acts bf16, off(k,b) = ((k>>3)*64+b)*8+(k&7).
// Per group of 128 k: 4 MFMA K-steps, pq16 on acc, atomicAdd into accg[o][b].
template <int D, int GPB>
__global__ __launch_bounds__(256)
void k_fc_mfma(const unsigned short* __restrict__ bpk, const float* __restrict__ w,
               float* __restrict__ accg) {
    const int lane = threadIdx.x & 63, wv = threadIdx.x >> 6;
    const int n = lane & 15, kb = lane >> 4;
    const int orow = blockIdx.x * 64 + wv * 16 + n;
    const int g0 = blockIdx.y * GPB;

    float tot[4][4];
    #pragma unroll
    for (int s = 0; s < 4; ++s)
        #pragma unroll
        for (int r = 0; r < 4; ++r) tot[s][r] = 0.f;

    #pragma unroll 1
    for (int g = 0; g < GPB; ++g) {
        const int kbase = (g0 + g) * 128;
        f32x4 a0 = {0,0,0,0}, a1 = {0,0,0,0}, a2 = {0,0,0,0}, a3 = {0,0,0,0};
        #pragma unroll
        for (int s = 0; s < 4; ++s) {
            const int k0 = kbase + s * 32 + kb * 8;
            const float* wp = w + (size_t)orow * D + k0;
            float4 wlo = *(const float4*)wp;
            float4 whi = *(const float4*)(wp + 4);
            bf16x8 af;
            af[0] = (short)sgn_bf16(wlo.x); af[1] = (short)sgn_bf16(wlo.y);
            af[2] = (short)sgn_bf16(wlo.z); af[3] = (short)sgn_bf16(wlo.w);
            af[4] = (short)sgn_bf16(whi.x); af[5] = (short)sgn_bf16(whi.y);
            af[6] = (short)sgn_bf16(whi.z); af[7] = (short)sgn_bf16(whi.w);
            const unsigned short* bp = bpk + (size_t)(k0 >> 3) * 512;
            bf16x8 b0 = *(const bf16x8*)(bp + (n +  0) * 8);
            bf16x8 b1 = *(const bf16x8*)(bp + (n + 16) * 8);
            bf16x8 b2 = *(const bf16x8*)(bp + (n + 32) * 8);
            bf16x8 b3 = *(const bf16x8*)(bp + (n + 48) * 8);
            a0 = __builtin_amdgcn_mfma_f32_16x16x32_bf16(af, b0, a0, 0, 0, 0);
            a1 = __builtin_amdgcn_mfma_f32_16x16x32_bf16(af, b1, a1, 0, 0, 0);
            a2 = __builtin_amdgcn_mfma_f32_16x16x32_bf16(af, b2, a2, 0, 0, 0);
            a3 = __builtin_amdgcn_mfma_f32_16x16x32_bf16(af, b3, a3, 0, 0, 0);
        }
        #pragma unroll
        for (int r = 0; r < 4; ++r) {
            tot[0][r] += pq16(a0[r]); tot[1][r] += pq16(a1[r]);
            tot[2][r] += pq16(a2[r]); tot[3][r] += pq16(a3[r]);
        }
    }
    const int od = blockIdx.x * 64 + wv * 16 + kb * 4;
    #pragma unroll
    for (int s = 0; s < 4; ++s)
        #pragma unroll
        for (int r = 0; r < 4; ++r)
            atomicAdd(&accg[(size_t)(od + r) * 64 + s * 16 + n], tot[s][r]);
}

// ---------------- fc epilogue: bn (+sign+pack) ------------------------------
template <bool SIGN>
__global__ __launch_bounds__(256)
void k_fc_ep(const float* __restrict__ accg, const float* __restrict__ bnp,
             unsigned short* __restrict__ packed, float* __restrict__ h2, int O) {
    int idx = blockIdx.x * 256 + threadIdx.x;   // O*64
    int b = idx & 63, o = idx >> 6;
    float val = bnv(accg[idx], bnp[o], bnp[O + o], bnp[2 * O + o], bnp[3 * O + o]);
    if (SIGN) packed[((size_t)(o >> 3) * 64 + b) * 8 + (o & 7)] = sgn_bf16(val);
    else      h2[(size_t)b * 1024 + o] = val;
}

// ---------------- final dense + bias + bn: one wave per (b,o) ---------------
__global__ __launch_bounds__(64)
void k_out(const float* __restrict__ h2, const float* __restrict__ ow,
           const float* __restrict__ ob, const float* __restrict__ bnp,
           float* __restrict__ out) {
    int b = blockIdx.x / 10, o = blockIdx.x % 10;
    int lane = threadIdx.x;
    float acc = 0.f;
    #pragma unroll
    for (int i = 0; i < 16; ++i) {
        int k = i * 64 + lane;
        acc += h2[b * 1024 + k] * ow[o * 1024 + k];
    }
    #pragma unroll
    for (int off = 32; off; off >>= 1) acc += __shfl_xor(acc, off);
    if (lane == 0)
        out[b * 10 + o] = bnv(acc + ob[o], bnp[o], bnp[10 + o], bnp[20 + o], bnp[30 + o]);
}

extern "C" void kernel_launch(void* const* d_in, const int* in_sizes, int n_in,
                              void* d_out, int out_size, void* d_ws, size_t ws_size,
                              hipStream_t stream) {
    const float* x     = (const float*)d_in[0];
    const float* w0    = (const float*)d_in[1];
    const float* bn0   = (const float*)d_in[2];
    const float* w1    = (const float*)d_in[3];
    const float* bn1   = (const float*)d_in[4];
    const float* w2    = (const float*)d_in[5];
    const float* bn2   = (const float*)d_in[6];
    const float* w3    = (const float*)d_in[7];
    const float* bn3   = (const float*)d_in[8];
    const float* w4    = (const float*)d_in[9];
    const float* bn4   = (const float*)d_in[10];
    const float* w5    = (const float*)d_in[11];
    const float* bn5   = (const float*)d_in[12];
    const float* fc1w  = (const float*)d_in[13];
    const float* bnf1  = (const float*)d_in[14];
    const float* fc2w  = (const float*)d_in[15];
    const float* bnf2  = (const float*)d_in[16];
    const float* outw  = (const float*)d_in[17];
    const float* outb  = (const float*)d_in[18];
    const float* bnout = (const float*)d_in[19];

    char* ws = (char*)d_ws;
    unsigned short* actA  = (unsigned short*)(ws);              // 16,777,216 B
    unsigned short* actB  = (unsigned short*)(ws + 16777216);   //  4,194,304 B
    unsigned short* wpk   = (unsigned short*)(ws + 20971520);   //  6,291,456 B
    unsigned short* a5p   = (unsigned short*)(ws + 27262976);   //  1,048,576 B [8192 k][64 b] packed
    unsigned short* a6p   = (unsigned short*)(ws + 28311552);   //    131,072 B [1024 k][64 b] packed
    float*          h1acc = (float*)(ws + 28442624);            //    262,144 B [1024 o][64 b]
    float*          h2acc = (float*)(ws + 28704768);            //    262,144 B [1024 o][64 b]
    float*          h2    = (float*)(ws + 28966912);            //    262,144 B [64 b][1024 o]

    const unsigned int* actA32 = (const unsigned int*)actA;
    const unsigned int* actB32 = (const unsigned int*)actB;
    const unsigned int* wpk32  = (const unsigned int*)wpk;

    hipMemsetAsync(h1acc, 0, 262144, stream);
    hipMemsetAsync(h2acc, 0, 262144, stream);

    // conv0 + bn0 + sign -> actA NHWC bf16 [64,32,32,128]
    k_conv0<<<dim3(32768), dim3(256), 0, stream>>>(x, w0, bn0, actA);

    // L1: 128->128 @32, pool -> actB [64,16,16,128]
    k_pack_w<<<dim3(800), dim3(256), 0, stream>>>(w1, wpk, 128, 128, 10);
    k_conv_mfma<32, 32, 128, 128, 10, 8, 16, 1>
        <<<dim3(8, 2, 64), dim3(256), 0, stream>>>(actA32, wpk32, bn1, actB, nullptr);

    // L2: 128->256 @16 -> actA [64,16,16,256]
    k_pack_w<<<dim3(1600), dim3(256), 0, stream>>>(w2, wpk, 128, 256, 10);
    k_conv_mfma<16, 16, 128, 256, 10, 8, 16, 0>
        <<<dim3(2, 4, 64), dim3(256), 0, stream>>>(actB32, wpk32, bn2, actA, nullptr);

    // L3: 256->256 @16, pool -> actB [64,8,8,256]
    k_pack_w<<<dim3(3040), dim3(256), 0, stream>>>(w3, wpk, 256, 256, 19);
    k_conv_mfma<16, 16, 256, 256, 19, 8, 16, 1>
        <<<dim3(2, 4, 64), dim3(256), 0, stream>>>(actA32, wpk32, bn3, actB, nullptr);

    // L4: 256->512 @8 -> actA [64,8,8,512]
    k_pack_w<<<dim3(6080), dim3(256), 0, stream>>>(w4, wpk, 256, 512, 19);
    k_conv_mfma<8, 8, 256, 512, 19, 8, 8, 0>
        <<<dim3(1, 8, 64), dim3(256), 0, stream>>>(actB32, wpk32, bn4, actA, nullptr);

    // L5: 512->512 @8, pool -> a5p packed [8192][64]
    k_pack_w<<<dim3(11840), dim3(256), 0, stream>>>(w5, wpk, 512, 512, 37);
    k_conv_mfma<8, 8, 512, 512, 37, 8, 8, 2>
        <<<dim3(1, 8, 64), dim3(256), 0, stream>>>(actA32, wpk32, bn5, nullptr, a5p);

    // fc1: D=8192, 16 o-tiles x 16 k-chunks (4 groups each)
    k_fc_mfma<8192, 4><<<dim3(16, 16), dim3(256), 0, stream>>>(a5p, fc1w, h1acc);
    k_fc_ep<true><<<dim3(256), dim3(256), 0, stream>>>(h1acc, bnf1, a6p, nullptr, 1024);

    // fc2: D=1024, 16 o-tiles x 8 k-chunks (1 group each)
    k_fc_mfma<1024, 1><<<dim3(16, 8), dim3(256), 0, stream>>>(a6p, fc2w, h2acc);
    k_fc_ep<false><<<dim3(256), dim3(256), 0, stream>>>(h2acc, bnf2, nullptr, h2, 1024);

    // out
    k_out<<<dim3(640), dim3(64), 0, stream>>>(h2, outw, outb, bnout, (float*)d_out);
}

// Round 5
// 298.183 us; speedup vs baseline: 12.8504x; 2.1528x over previous
//
#include <hip/hip_runtime.h>
#include <cstdint>
#include <cstddef>

using bf16x8 = __attribute__((ext_vector_type(8))) short;
using f32x4  = __attribute__((ext_vector_type(4))) float;
using u32x4  = __attribute__((ext_vector_type(4))) unsigned int;

#define DI __device__ __forceinline__

// psum ADC quantization: clip(round_half_even(p/16), -8, 7) * 16   (exact on int psums)
DI float pq16(float ps) {
    float q = rintf(ps * 0.0625f);
    q = fminf(7.f, fmaxf(-8.f, q));
    return q * 16.f;
}

DI float bnv(float x, float g, float b, float m, float v) {
    return (x - m) * (g / sqrtf(v + 1e-5f)) + b;
}

DI unsigned short sgn_bf16(float v) {
    return (v >= 0.f) ? (unsigned short)0x3F80 : (unsigned short)0xBF80;
}

// ---------------- conv0 (full precision) + bn0 + sign -> bf16 NHWC ----------
// block = (b, y); thread: o = tid&127, xc = tid>>7 (16 x-outputs each).
// x window staged in LDS (broadcast reads), weights in VGPRs.
__global__ __launch_bounds__(256)
void k_conv0(const float* __restrict__ x, const float* __restrict__ w,
             const float* __restrict__ bnp, unsigned short* __restrict__ out) {
    __shared__ float sX[3][3][36];   // [c][row y-1..y+1][col gx+1, 0..33]
    const int b = blockIdx.x >> 5, y = blockIdx.x & 31;
    const int tid = threadIdx.x;
    const int o = tid & 127, xc = tid >> 7;

    for (int i = tid; i < 3 * 3 * 36; i += 256) {
        int col = i % 36, rr = (i / 36) % 3, c = i / 108;
        int gy = y + rr - 1, gx = col - 1;
        float v = 0.f;
        if ((unsigned)gy < 32u && (unsigned)gx < 32u)
            v = x[((b * 3 + c) * 32 + gy) * 32 + gx];
        sX[c][rr][col] = v;
    }
    float wr[27];
    const float* wp = w + o * 27;
    #pragma unroll
    for (int t = 0; t < 27; ++t) wr[t] = wp[t];
    __syncthreads();

    const float bg = bnp[o], bb = bnp[128 + o], bm = bnp[256 + o], bv = bnp[384 + o];
    unsigned short* op = out + ((size_t)(b * 32 + y) * 32) * 128 + o;

    #pragma unroll
    for (int q = 0; q < 4; ++q) {
        float acc0 = 0.f, acc1 = 0.f, acc2 = 0.f, acc3 = 0.f;
        const int X0 = xc * 16 + q * 4;
        #pragma unroll
        for (int c = 0; c < 3; ++c)
            #pragma unroll
            for (int ky = 0; ky < 3; ++ky) {
                float xv0 = sX[c][ky][X0 + 0], xv1 = sX[c][ky][X0 + 1];
                float xv2 = sX[c][ky][X0 + 2], xv3 = sX[c][ky][X0 + 3];
                float xv4 = sX[c][ky][X0 + 4], xv5 = sX[c][ky][X0 + 5];
                float w0 = wr[c * 9 + ky * 3 + 0];
                float w1 = wr[c * 9 + ky * 3 + 1];
                float w2 = wr[c * 9 + ky * 3 + 2];
                acc0 += xv0 * w0 + xv1 * w1 + xv2 * w2;
                acc1 += xv1 * w0 + xv2 * w1 + xv3 * w2;
                acc2 += xv2 * w0 + xv3 * w1 + xv4 * w2;
                acc3 += xv3 * w0 + xv4 * w1 + xv5 * w2;
            }
        op[(size_t)(X0 + 0) * 128] = sgn_bf16(bnv(acc0, bg, bb, bm, bv));
        op[(size_t)(X0 + 1) * 128] = sgn_bf16(bnv(acc1, bg, bb, bm, bv));
        op[(size_t)(X0 + 2) * 128] = sgn_bf16(bnv(acc2, bg, bb, bm, bv));
        op[(size_t)(X0 + 3) * 128] = sgn_bf16(bnv(acc3, bg, bb, bm, bv));
    }
}

// ---------------- weight sign-pack: wpk[g][o][tap(10)][c(16)] bf16 ----------
__global__ __launch_bounds__(256)
void k_pack_w(const float* __restrict__ w, unsigned short* __restrict__ wpk,
              int Cin, int O, int G) {
    int idx = blockIdx.x * 256 + threadIdx.x;
    int total = G * O * 160;
    if (idx >= total) return;
    int c = idx & 15;
    int tap = (idx >> 4) % 10;
    int rest = idx / 160;
    int o = rest % O, g = rest / O;
    unsigned short v = 0;
    int cg = g * 14 + c;
    if (tap < 9 && c < 14 && cg < Cin)
        v = sgn_bf16(w[((size_t)o * Cin + cg) * 9 + tap]);
    wpk[idx] = v;
}

// ---------------- MFMA crossbar psum conv, fused bn/sign/pool epilogue ------
// act NHWC bf16 (read as u32). K-order per group: tap-major (10, tap9=zero pad),
// channel-minor (16, ch>=14 or >=Cin zero). 5 MFMA K-steps of 32 per group.
// Weights read directly from global per-lane (L2-shared across b-blocks).
// POOLMODE: 0 = bn+sign -> act NHWC; 1 = pool2+bn+sign -> act NHWC (RW==16);
//           2 = pool2+bn+sign -> a5p B-packed bf16 (RW==8, layer5)
template <int H, int W, int Cin, int O, int G, int RH, int RW, int POOLMODE>
__global__ __launch_bounds__(256)
void k_conv_mfma(const unsigned int* __restrict__ act,
                 const unsigned short* __restrict__ wpk,
                 const float* __restrict__ bnp,
                 unsigned short* __restrict__ outa,
                 unsigned short* __restrict__ a5p) {
    constexpr int SH = RH + 2, SW = RW + 2;
    constexpr int MS = RH * RW / 16;          // 16-pixel M-subtiles per region
    constexpr int NREGX = W / RW;
    static_assert(POOLMODE != 1 || RW == 16, "pool mode 1 needs RW=16");
    static_assert(POOLMODE != 2 || (RW == 8 && MS == 4), "pool mode 2 needs 8x8");

    __shared__ __align__(16) unsigned int sA[SH * SW * 12];  // 48B per pixel slot

    const int tid  = threadIdx.x;
    const int regY = (int)blockIdx.x / NREGX, regX = (int)blockIdx.x % NREGX;
    const int o0   = blockIdx.y * 64;
    const int b    = blockIdx.z;

    const int lane = tid & 63, wv = tid >> 6;
    const int n  = lane & 15;
    const int kb = lane >> 4;
    const int hb = kb >> 1, ch = kb & 1;

    int baseA[MS];
    #pragma unroll
    for (int ms = 0; ms < MS; ++ms) {
        int p = ms * 16 + n;
        int y = p / RW, x = p % RW;
        baseA[ms] = (y * SW + x) * 48 + ch * 16;
    }

    float tot[MS][4];
    #pragma unroll
    for (int ms = 0; ms < MS; ++ms) {
        tot[ms][0] = 0.f; tot[ms][1] = 0.f; tot[ms][2] = 0.f; tot[ms][3] = 0.f;
    }

    // per-lane weight row base (o = o0 + wv*16 + n)
    const unsigned short* wrow = wpk + ((size_t)o0 + wv * 16 + n) * 160 + ch * 8;

    #pragma unroll 1
    for (int g = 0; g < G; ++g) {
        const int rem_dw = (Cin - g * 14) >> 1;
        for (int i = tid; i < SH * SW * 8; i += 256) {
            int cp = i & 7, slot = i >> 3;
            int yy = slot / SW, xx = slot - yy * SW;
            int gy = regY * RH + yy - 1, gx = regX * RW + xx - 1;
            unsigned int v = 0;
            if (cp < 7 && cp < rem_dw &&
                (unsigned)gy < (unsigned)H && (unsigned)gx < (unsigned)W)
                v = act[(((size_t)b * H + gy) * W + gx) * (Cin / 2) + g * 7 + cp];
            sA[slot * 12 + cp] = v;
        }
        // B fragments straight from global (no LDS round-trip)
        const unsigned short* wg = wrow + (size_t)g * O * 160;
        bf16x8 bq[5];
        #pragma unroll
        for (int s = 0; s < 5; ++s) {
            int tap = 2 * s + hb;
            bq[s] = *(const bf16x8*)(wg + tap * 16);
        }
        __syncthreads();

        const char* sAc = (const char*)sA;
        #pragma unroll
        for (int ms = 0; ms < MS; ++ms) {
            f32x4 acc = {0.f, 0.f, 0.f, 0.f};
            #pragma unroll
            for (int s = 0; s < 5; ++s) {
                const int t0 = 2 * s, t1 = 2 * s + 1;
                const int off0 = ((t0 / 3) * SW + (t0 % 3)) * 48;
                const int off1 = (t1 >= 9) ? 0 : ((t1 / 3) * SW + (t1 % 3)) * 48;
                int off = hb ? off1 : off0;
                bf16x8 af = *(const bf16x8*)(sAc + baseA[ms] + off);
                acc = __builtin_amdgcn_mfma_f32_16x16x32_bf16(af, bq[s], acc, 0, 0, 0);
            }
            tot[ms][0] += pq16(acc[0]);
            tot[ms][1] += pq16(acc[1]);
            tot[ms][2] += pq16(acc[2]);
            tot[ms][3] += pq16(acc[3]);
        }
        __syncthreads();
    }

    const int oc = o0 + wv * 16 + n;
    const float bg = bnp[oc], bb = bnp[O + oc], bm = bnp[2 * O + oc], bvr = bnp[3 * O + oc];

    if constexpr (POOLMODE == 0) {
        #pragma unroll
        for (int ms = 0; ms < MS; ++ms)
            #pragma unroll
            for (int r = 0; r < 4; ++r) {
                int p = ms * 16 + 4 * kb + r;
                int y = regY * RH + p / RW, x = regX * RW + p % RW;
                float val = bnv(tot[ms][r], bg, bb, bm, bvr);
                outa[(((size_t)b * H + y) * W + x) * O + oc] = sgn_bf16(val);
            }
    } else if constexpr (POOLMODE == 1) {
        #pragma unroll
        for (int j = 0; j < MS / 2; ++j)
            #pragma unroll
            for (int q = 0; q < 2; ++q) {
                float v = fmaxf(fmaxf(tot[2 * j][2 * q], tot[2 * j][2 * q + 1]),
                                fmaxf(tot[2 * j + 1][2 * q], tot[2 * j + 1][2 * q + 1]));
                float val = bnv(v, bg, bb, bm, bvr);
                int py = regY * (RH / 2) + j, px = regX * (RW / 2) + 2 * kb + q;
                outa[(((size_t)b * (H / 2) + py) * (W / 2) + px) * O + oc] = sgn_bf16(val);
            }
    } else {
        #pragma unroll
        for (int ms = 0; ms < MS; ++ms)
            #pragma unroll
            for (int q = 0; q < 2; ++q) {
                float h = fmaxf(tot[ms][2 * q], tot[ms][2 * q + 1]);
                float o2 = __shfl_xor(h, 32);
                float v = fmaxf(h, o2);
                if (hb == 0) {
                    float val = bnv(v, bg, bb, bm, bvr);
                    int d = oc * 16 + ms * 4 + 2 * ch + q;   // NCHW flatten order
                    a5p[((size_t)(d >> 3) * 64 + b) * 8 + (d & 7)] = sgn_bf16(val);
                }
            }
    }
}

// ---------------- MFMA psum fc: wave owns 16 o-rows x 64 batch --------------
// bpk: B-packed acts bf16, off(k,b) = ((k>>3)*64+b)*8+(k&7).
// Per group of 128 k: 4 MFMA K-steps, pq16 on acc, atomicAdd into accg[o][b].
template <int D, int GPB>
__global__ __launch_bounds__(256)
void k_fc_mfma(const unsigned short* __restrict__ bpk, const float* __restrict__ w,
               float* __restrict__ accg) {
    const int lane = threadIdx.x & 63, wv = threadIdx.x >> 6;
    const int n = lane & 15, kb = lane >> 4;
    const int orow = blockIdx.x * 64 + wv * 16 + n;
    const int g0 = blockIdx.y * GPB;

    float tot[4][4];
    #pragma unroll
    for (int s = 0; s < 4; ++s)
        #pragma unroll
        for (int r = 0; r < 4; ++r) tot[s][r] = 0.f;

    #pragma unroll 1
    for (int g = 0; g < GPB; ++g) {
        const int kbase = (g0 + g) * 128;
        f32x4 a0 = {0,0,0,0}, a1 = {0,0,0,0}, a2 = {0,0,0,0}, a3 = {0,0,0,0};
        #pragma unroll
        for (int s = 0; s < 4; ++s) {
            const int k0 = kbase + s * 32 + kb * 8;
            const float* wp = w + (size_t)orow * D + k0;
            float4 wlo = *(const float4*)wp;
            float4 whi = *(const float4*)(wp + 4);
            bf16x8 af;
            af[0] = (short)sgn_bf16(wlo.x); af[1] = (short)sgn_bf16(wlo.y);
            af[2] = (short)sgn_bf16(wlo.z); af[3] = (short)sgn_bf16(wlo.w);
            af[4] = (short)sgn_bf16(whi.x); af[5] = (short)sgn_bf16(whi.y);
            af[6] = (short)sgn_bf16(whi.z); af[7] = (short)sgn_bf16(whi.w);
            const unsigned short* bp = bpk + (size_t)(k0 >> 3) * 512;
            bf16x8 b0 = *(const bf16x8*)(bp + (n +  0) * 8);
            bf16x8 b1 = *(const bf16x8*)(bp + (n + 16) * 8);
            bf16x8 b2 = *(const bf16x8*)(bp + (n + 32) * 8);
            bf16x8 b3 = *(const bf16x8*)(bp + (n + 48) * 8);
            a0 = __builtin_amdgcn_mfma_f32_16x16x32_bf16(af, b0, a0, 0, 0, 0);
            a1 = __builtin_amdgcn_mfma_f32_16x16x32_bf16(af, b1, a1, 0, 0, 0);
            a2 = __builtin_amdgcn_mfma_f32_16x16x32_bf16(af, b2, a2, 0, 0, 0);
            a3 = __builtin_amdgcn_mfma_f32_16x16x32_bf16(af, b3, a3, 0, 0, 0);
        }
        #pragma unroll
        for (int r = 0; r < 4; ++r) {
            tot[0][r] += pq16(a0[r]); tot[1][r] += pq16(a1[r]);
            tot[2][r] += pq16(a2[r]); tot[3][r] += pq16(a3[r]);
        }
    }
    const int od = blockIdx.x * 64 + wv * 16 + kb * 4;
    #pragma unroll
    for (int s = 0; s < 4; ++s)
        #pragma unroll
        for (int r = 0; r < 4; ++r)
            atomicAdd(&accg[(size_t)(od + r) * 64 + s * 16 + n], tot[s][r]);
}

// ---------------- fc epilogue: bn (+sign+pack) ------------------------------
template <bool SIGN>
__global__ __launch_bounds__(256)
void k_fc_ep(const float* __restrict__ accg, const float* __restrict__ bnp,
             unsigned short* __restrict__ packed, float* __restrict__ h2, int O) {
    int idx = blockIdx.x * 256 + threadIdx.x;   // O*64
    int b = idx & 63, o = idx >> 6;
    float val = bnv(accg[idx], bnp[o], bnp[O + o], bnp[2 * O + o], bnp[3 * O + o]);
    if (SIGN) packed[((size_t)(o >> 3) * 64 + b) * 8 + (o & 7)] = sgn_bf16(val);
    else      h2[(size_t)b * 1024 + o] = val;
}

// ---------------- final dense + bias + bn: one wave per (b,o) ---------------
__global__ __launch_bounds__(64)
void k_out(const float* __restrict__ h2, const float* __restrict__ ow,
           const float* __restrict__ ob, const float* __restrict__ bnp,
           float* __restrict__ out) {
    int b = blockIdx.x / 10, o = blockIdx.x % 10;
    int lane = threadIdx.x;
    float acc = 0.f;
    #pragma unroll
    for (int i = 0; i < 16; ++i) {
        int k = i * 64 + lane;
        acc += h2[b * 1024 + k] * ow[o * 1024 + k];
    }
    #pragma unroll
    for (int off = 32; off; off >>= 1) acc += __shfl_xor(acc, off);
    if (lane == 0)
        out[b * 10 + o] = bnv(acc + ob[o], bnp[o], bnp[10 + o], bnp[20 + o], bnp[30 + o]);
}

extern "C" void kernel_launch(void* const* d_in, const int* in_sizes, int n_in,
                              void* d_out, int out_size, void* d_ws, size_t ws_size,
                              hipStream_t stream) {
    const float* x     = (const float*)d_in[0];
    const float* w0    = (const float*)d_in[1];
    const float* bn0   = (const float*)d_in[2];
    const float* w1    = (const float*)d_in[3];
    const float* bn1   = (const float*)d_in[4];
    const float* w2    = (const float*)d_in[5];
    const float* bn2   = (const float*)d_in[6];
    const float* w3    = (const float*)d_in[7];
    const float* bn3   = (const float*)d_in[8];
    const float* w4    = (const float*)d_in[9];
    const float* bn4   = (const float*)d_in[10];
    const float* w5    = (const float*)d_in[11];
    const float* bn5   = (const float*)d_in[12];
    const float* fc1w  = (const float*)d_in[13];
    const float* bnf1  = (const float*)d_in[14];
    const float* fc2w  = (const float*)d_in[15];
    const float* bnf2  = (const float*)d_in[16];
    const float* outw  = (const float*)d_in[17];
    const float* outb  = (const float*)d_in[18];
    const float* bnout = (const float*)d_in[19];

    char* ws = (char*)d_ws;
    unsigned short* actA  = (unsigned short*)(ws);              // 16,777,216 B
    unsigned short* actB  = (unsigned short*)(ws + 16777216);   //  4,194,304 B
    unsigned short* wpk   = (unsigned short*)(ws + 20971520);   //  6,291,456 B
    unsigned short* a5p   = (unsigned short*)(ws + 27262976);   //  1,048,576 B [8192 k][64 b] packed
    unsigned short* a6p   = (unsigned short*)(ws + 28311552);   //    131,072 B [1024 k][64 b] packed
    float*          h1acc = (float*)(ws + 28442624);            //    262,144 B [1024 o][64 b]
    float*          h2acc = (float*)(ws + 28704768);            //    262,144 B [1024 o][64 b]
    float*          h2    = (float*)(ws + 28966912);            //    262,144 B [64 b][1024 o]

    const unsigned int* actA32 = (const unsigned int*)actA;
    const unsigned int* actB32 = (const unsigned int*)actB;

    hipMemsetAsync(h1acc, 0, 262144, stream);
    hipMemsetAsync(h2acc, 0, 262144, stream);

    // conv0 + bn0 + sign -> actA NHWC bf16 [64,32,32,128]
    k_conv0<<<dim3(2048), dim3(256), 0, stream>>>(x, w0, bn0, actA);

    // L1: 128->128 @32, pool -> actB [64,16,16,128]
    k_pack_w<<<dim3(800), dim3(256), 0, stream>>>(w1, wpk, 128, 128, 10);
    k_conv_mfma<32, 32, 128, 128, 10, 8, 16, 1>
        <<<dim3(8, 2, 64), dim3(256), 0, stream>>>(actA32, wpk, bn1, actB, nullptr);

    // L2: 128->256 @16 -> actA [64,16,16,256]
    k_pack_w<<<dim3(1600), dim3(256), 0, stream>>>(w2, wpk, 128, 256, 10);
    k_conv_mfma<16, 16, 128, 256, 10, 8, 16, 0>
        <<<dim3(2, 4, 64), dim3(256), 0, stream>>>(actB32, wpk, bn2, actA, nullptr);

    // L3: 256->256 @16, pool -> actB [64,8,8,256]
    k_pack_w<<<dim3(3040), dim3(256), 0, stream>>>(w3, wpk, 256, 256, 19);
    k_conv_mfma<16, 16, 256, 256, 19, 8, 16, 1>
        <<<dim3(2, 4, 64), dim3(256), 0, stream>>>(actA32, wpk, bn3, actB, nullptr);

    // L4: 256->512 @8 -> actA [64,8,8,512]
    k_pack_w<<<dim3(6080), dim3(256), 0, stream>>>(w4, wpk, 256, 512, 19);
    k_conv_mfma<8, 8, 256, 512, 19, 8, 8, 0>
        <<<dim3(1, 8, 64), dim3(256), 0, stream>>>(actB32, wpk, bn4, actA, nullptr);

    // L5: 512->512 @8, pool -> a5p packed [8192][64]
    k_pack_w<<<dim3(11840), dim3(256), 0, stream>>>(w5, wpk, 512, 512, 37);
    k_conv_mfma<8, 8, 512, 512, 37, 8, 8, 2>
        <<<dim3(1, 8, 64), dim3(256), 0, stream>>>(actA32, wpk, bn5, nullptr, a5p);

    // fc1: D=8192, 16 o-tiles x 16 k-chunks (4 groups each)
    k_fc_mfma<8192, 4><<<dim3(16, 16), dim3(256), 0, stream>>>(a5p, fc1w, h1acc);
    k_fc_ep<true><<<dim3(256), dim3(256), 0, stream>>>(h1acc, bnf1, a6p, nullptr, 1024);

    // fc2: D=1024, 16 o-tiles x 8 k-chunks (1 group each)
    k_fc_mfma<1024, 1><<<dim3(16, 8), dim3(256), 0, stream>>>(a6p, fc2w, h2acc);
    k_fc_ep<false><<<dim3(256), dim3(256), 0, stream>>>(h2acc, bnf2, nullptr, h2, 1024);

    // out
    k_out<<<dim3(640), dim3(64), 0, stream>>>(h2, outw, outb, bnout, (float*)d_out);
}